// Round 2
// baseline (275.094 us; speedup 1.0000x reference)
//
#include <hip/hip_runtime.h>

#define BINS 25
#define H 512
#define W 512
#define NPLANES 96   // B*C = 32*3
#define NSH 32       // sub-histograms per block
#define BPP 4        // blocks per plane: 768 blocks = 3/CU, 3 waves/SIMD

// Block = 256 threads = 4 waves; logical block b covers plane z = b>>2,
// y-strips 4*(b&3) .. 4*(b&3)+3 (one 16-output-row strip per wave).
// Thread: x-lane i = tid&63 owns output cols 4i..4i+3; walks 16 output rows.
// Software pipeline: 3 loop-carried slot-pairs (A,B,C) of RAW quads keep
// 16-24 dwordx4 loads in flight per wave (VGPR ~150); h-blur happens at
// consume time, 3 half-iters after issue. This is the MLP fix for the
// 36-VGPR serialized-load version (85us, VALUBusy 16%).
__global__ __launch_bounds__(256, 3) void blur_hist(
        const float* __restrict__ x, const float* __restrict__ y,
        unsigned int* __restrict__ partial) {
    // XCD-contiguous swizzle (768 % 8 == 0 -> bijective): same-plane blocks
    // land on one XCD's L2 for halo reuse.
    const int b = ((blockIdx.x & 7) * 96) + (blockIdx.x >> 3);
    const int z = b >> 2;
    const float* src = (z < NPLANES) ? x + (size_t)z * H * W
                                     : y + (size_t)(z - NPLANES) * H * W;

    __shared__ unsigned int sh[NSH * BINS];   // 3.2 KB
    const int tid = threadIdx.x;
    if (tid < (NSH * BINS / 4))
        *(float4*)((float*)sh + 4 * tid) = make_float4(0.f, 0.f, 0.f, 0.f);
    __syncthreads();

    const int i = tid & 63;                   // x-lane
    const int s = (b & 3) * 4 + (tid >> 6);   // y-strip 0..15 (wave-uniform)
    const int c0 = 8 * i - 4;                 // col of quad0
    const int o0 = (i == 0)  ? 0   : c0;      // clamped quad0 col
    const int o3 = (i == 63) ? 508 : c0 + 12; // clamped quad3 col
    const float m0 = (i == 0)  ? 0.f : 1.f;   // zero-mask for left halo
    const float m3 = (i == 63) ? 0.f : 1.f;   // zero-mask for right halo

    const float w0 = 1.f/64.f, w1 = 6.f/64.f, w2 = 15.f/64.f, w3 = 20.f/64.f;

    // raw (un-blurred) quad load of input row gy; zero for OOB rows
    auto RAW = [&](int gy, float4& qa, float4& qb, float4& qc, float4& qd) {
        if ((unsigned)gy < (unsigned)H) {     // wave-uniform branch
            const float* rp = src + (size_t)gy * W;
            qa = *(const float4*)(rp + o0);
            qb = *(const float4*)(rp + c0 + 4);
            qc = *(const float4*)(rp + c0 + 8);
            qd = *(const float4*)(rp + o3);
        } else {
            qa = qb = qc = qd = make_float4(0.f, 0.f, 0.f, 0.f);
        }
    };
    // horizontal 7-tap blur (stride 2) of one raw row -> 4 output cols
    auto HB = [&](const float4& qa, const float4& qb,
                  const float4& qc, const float4& qd) -> float4 {
        float r1 = qa.y * m0, r2 = qa.z * m0, r3 = qa.w * m0;
        float r4 = qb.x, r5 = qb.y, r6 = qb.z, r7 = qb.w;
        float r8 = qc.x, r9 = qc.y, r10 = qc.z, r11 = qc.w;
        float r12 = qd.x * m3, r13 = qd.y * m3;
        float4 h;
        h.x = w0*(r1 + r7)  + w1*(r2 + r6)  + w2*(r3 + r5)  + w3*r4;
        h.y = w0*(r3 + r9)  + w1*(r4 + r8)  + w2*(r5 + r7)  + w3*r6;
        h.z = w0*(r5 + r11) + w1*(r6 + r10) + w2*(r7 + r9)  + w3*r8;
        h.w = w0*(r7 + r13) + w1*(r8 + r12) + w2*(r9 + r11) + w3*r10;
        return h;
    };

    unsigned int* wh = sh + (tid & (NSH - 1)) * BINS;
    auto binit = [&](float v) {
        int bb = min((int)(v * 25.f), BINS - 1);   // v in [0,1] by construction
        atomicAdd(&wh[bb], 1u);
    };
    auto vout = [&](const float4& h0, const float4& h1, const float4& h2,
                    const float4& h3, const float4& h4, const float4& h5,
                    const float4& h6) {
        binit(w0*(h0.x+h6.x) + w1*(h1.x+h5.x) + w2*(h2.x+h4.x) + w3*h3.x);
        binit(w0*(h0.y+h6.y) + w1*(h1.y+h5.y) + w2*(h2.y+h4.y) + w3*h3.y);
        binit(w0*(h0.z+h6.z) + w1*(h1.z+h5.z) + w2*(h2.z+h4.z) + w3*h3.z);
        binit(w0*(h0.w+h6.w) + w1*(h1.w+h5.w) + w2*(h2.w+h4.w) + w3*h3.w);
    };

    const int gy0 = 32 * s - 3;

    // ---- prime the pipeline: rows gy0+7..gy0+12 (24 dwordx4 in flight) ----
    float4 A0,A1,A2,A3,A4,A5,A6,A7;
    float4 B0,B1,B2,B3,B4,B5,B6,B7;
    float4 C0,C1,C2,C3,C4,C5,C6,C7;
    RAW(gy0 + 7,  A0,A1,A2,A3);  RAW(gy0 + 8,  A4,A5,A6,A7);
    RAW(gy0 + 9,  B0,B1,B2,B3);  RAW(gy0 + 10, B4,B5,B6,B7);
    RAW(gy0 + 11, C0,C1,C2,C3);  RAW(gy0 + 12, C4,C5,C6,C7);

    // ---- prologue window: rows gy0..gy0+6 ----
    float4 h0, h1, h2, h3, h4, h5, h6;
    {
        float4 qa, qb, qc, qd;
        RAW(gy0 + 0, qa,qb,qc,qd); h0 = HB(qa,qb,qc,qd);
        RAW(gy0 + 1, qa,qb,qc,qd); h1 = HB(qa,qb,qc,qd);
        RAW(gy0 + 2, qa,qb,qc,qd); h2 = HB(qa,qb,qc,qd);
        RAW(gy0 + 3, qa,qb,qc,qd); h3 = HB(qa,qb,qc,qd);
        RAW(gy0 + 4, qa,qb,qc,qd); h4 = HB(qa,qb,qc,qd);
        RAW(gy0 + 5, qa,qb,qc,qd); h5 = HB(qa,qb,qc,qd);
        RAW(gy0 + 6, qa,qb,qc,qd); h6 = HB(qa,qb,qc,qd);
    }

    // ---- steady state: 12 half-iters; consume a slot issued 3 halves ago,
    //      reissue it 6 rows ahead. Loads stay in flight across the backedge.
    float4 hA, hB;
    #pragma unroll 1
    for (int j = 0; j < 4; j++) {
        const int r = gy0 + 6 * j;
        // consume A (rows r+7,r+8), reissue A <- rows r+13,r+14
        hA = HB(A0,A1,A2,A3); hB = HB(A4,A5,A6,A7);
        RAW(r + 13, A0,A1,A2,A3); RAW(r + 14, A4,A5,A6,A7);
        vout(h0,h1,h2,h3,h4,h5,h6);
        h0=h2; h1=h3; h2=h4; h3=h5; h4=h6; h5=hA; h6=hB;
        // consume B (rows r+9,r+10), reissue B <- rows r+15,r+16
        hA = HB(B0,B1,B2,B3); hB = HB(B4,B5,B6,B7);
        RAW(r + 15, B0,B1,B2,B3); RAW(r + 16, B4,B5,B6,B7);
        vout(h0,h1,h2,h3,h4,h5,h6);
        h0=h2; h1=h3; h2=h4; h3=h5; h4=h6; h5=hA; h6=hB;
        // consume C (rows r+11,r+12), reissue C <- rows r+17,r+18
        hA = HB(C0,C1,C2,C3); hB = HB(C4,C5,C6,C7);
        RAW(r + 17, C0,C1,C2,C3); RAW(r + 18, C4,C5,C6,C7);
        vout(h0,h1,h2,h3,h4,h5,h6);
        h0=h2; h1=h3; h2=h4; h3=h5; h4=h6; h5=hA; h6=hB;
    }
    // ---- epilogue: rows gy0+31..gy0+36, no reissue ----
    hA = HB(A0,A1,A2,A3); hB = HB(A4,A5,A6,A7);
    vout(h0,h1,h2,h3,h4,h5,h6);
    h0=h2; h1=h3; h2=h4; h3=h5; h4=h6; h5=hA; h6=hB;
    hA = HB(B0,B1,B2,B3); hB = HB(B4,B5,B6,B7);
    vout(h0,h1,h2,h3,h4,h5,h6);
    h0=h2; h1=h3; h2=h4; h3=h5; h4=h6; h5=hA; h6=hB;
    hA = HB(C0,C1,C2,C3); hB = HB(C4,C5,C6,C7);
    vout(h0,h1,h2,h3,h4,h5,h6);
    h0=h2; h1=h3; h2=h4; h3=h5; h4=h6; h5=hA; h6=hB;
    vout(h0,h1,h2,h3,h4,h5,h6);
    __syncthreads();

    // ---- one histogram writeout per block ----
    if (tid < BINS) {
        unsigned int acc = 0;
        #pragma unroll
        for (int g = 0; g < NSH; g++) acc += sh[g * BINS + tid];
        partial[b * BINS + tid] = acc;
    }
}

// 96 blocks x 64 threads: plane p gathers its 4 block-partials for x and y,
// cosine sim, atomic mean into out[0].
__global__ __launch_bounds__(64) void reduce_cos(
        const unsigned int* __restrict__ partial, float* __restrict__ out) {
    __shared__ float sa[BINS], sb[BINS];
    const int p = blockIdx.x;
    const int t = threadIdx.x;
    if (t < BINS) {
        unsigned int a = 0, bb = 0;
        #pragma unroll
        for (int j = 0; j < BPP; j++) {
            a  += partial[((size_t)p * BPP + j) * BINS + t];
            bb += partial[((size_t)(NPLANES + p) * BPP + j) * BINS + t];
        }
        sa[t] = (float)a;
        sb[t] = (float)bb;
    }
    __syncthreads();
    if (t == 0) {
        const float inv_hw = 1.0f / (float)(H * W);
        float dot = 0.f, nx = 0.f, ny = 0.f;
        for (int k = 0; k < BINS; k++) {
            float a = sa[k] * inv_hw;
            float c = sb[k] * inv_hw;
            dot += a * c;
            nx  += a * a;
            ny  += c * c;
        }
        nx = fmaxf(sqrtf(nx), 1e-6f);
        ny = fmaxf(sqrtf(ny), 1e-6f);
        atomicAdd(out, (dot / (nx * ny)) * (1.0f / (float)NPLANES));
    }
}

extern "C" void kernel_launch(void* const* d_in, const int* in_sizes, int n_in,
                              void* d_out, int out_size, void* d_ws, size_t ws_size,
                              hipStream_t stream) {
    const float* x = (const float*)d_in[0];
    const float* y = (const float*)d_in[1];
    float* out = (float*)d_out;

    unsigned int* partial = (unsigned int*)d_ws;   // [768][25] u32 = 76.8 KB

    hipMemsetAsync(out, 0, sizeof(float), stream);

    blur_hist<<<2 * NPLANES * BPP, 256, 0, stream>>>(x, y, partial);
    reduce_cos<<<NPLANES, 64, 0, stream>>>(partial, out);
}

// Round 3
// 220.735 us; speedup vs baseline: 1.2463x; 1.2463x over previous
//
#include <hip/hip_runtime.h>

#define BINS 25
#define H 512
#define W 512
#define NPLANES 96   // B*C = 32*3
#define NSH 32       // sub-histograms per block
#define BPP 4        // blocks per plane: 768 blocks = exactly 3/CU (LDS-capped)
#define RING 6       // LDS ring slots per wave (rows); 12 KB/wave

// Address-space typedefs for the global->LDS DMA builtin.
typedef const __attribute__((address_space(1))) void* gvp;
typedef __attribute__((address_space(3))) void* lvp;

// Block = 256 threads = 4 waves; block b covers plane z = b>>2, wave w owns
// strip S = 4*(b&3)+w (16 output rows, 37 input rows). Input rows are staged
// dense (unit-stride) into a per-wave 6-slot LDS ring via async
// global_load_lds (2 instrs/row, zero dest VGPRs), depth-counted with
// s_waitcnt vmcnt(6) -- never drained to 0 in the loop. Each raw row is
// ds_read exactly once (chunk-swizzled to kill the 16-way bank conflict),
// h-blurred, and kept in a 7-row register window; vertical blur + histogram
// as before. This replaces r1's 2x-amplified 32B-stride global reads and
// r2's scratch-spilled register pipeline.
__global__ __launch_bounds__(256) void blur_hist(
        const float* __restrict__ x, const float* __restrict__ y,
        unsigned int* __restrict__ partial) {
    // XCD-contiguous swizzle (768 % 8 == 0 -> bijective): same-plane blocks
    // share an XCD L2 for halo reuse.
    const int b = ((blockIdx.x & 7) * 96) + (blockIdx.x >> 3);
    const int z = b >> 2;
    const float* src = (z < NPLANES) ? x + (size_t)z * H * W
                                     : y + (size_t)(z - NPLANES) * H * W;

    __shared__ __align__(16) float ring[4][RING][512];   // 48 KB
    __shared__ unsigned int sh[NSH * BINS];              // 3.2 KB

    const int tid = threadIdx.x;
    if (tid < (NSH * BINS / 4))
        *(float4*)((float*)sh + 4 * tid) = make_float4(0.f, 0.f, 0.f, 0.f);
    __syncthreads();

    const int l  = tid & 63;                  // x-lane
    const int wv = tid >> 6;                  // wave 0..3
    const int S  = (b & 3) * 4 + wv;          // y-strip 0..15
    const int g0 = 32 * S - 3;                // first input row of the strip

    // Involutive chunk swizzle within a 2KB row (chunk = 16B): spreads the
    // stride-2-chunk reader pattern across all 8 bank groups.
    auto swz = [](int c) { return c ^ ((c >> 3) & 7) ^ (((c >> 6) & 1) << 2); };

    // DMA source offsets (floats), fixed across rows: lane l of instr k
    // fetches chunk swz(64k+l) so that LDS position q holds chunk swz(q).
    const int so0 = swz(l) * 4;
    const int so1 = swz(64 + l) * 4;

    float* const rbase = &ring[wv][0][0];

    // Stage input row index k (gy = g0+k, clamped; dummy rows keep the vmcnt
    // count uniform) into ring slot sl. 2x global_load_lds dwordx4.
    auto STAGE = [&](int k, int sl) {
        int gy = g0 + k;
        gy = min(max(gy, 0), H - 1);
        const float* rp = src + (size_t)gy * W;
        float* lp = rbase + sl * 512;
        __builtin_amdgcn_global_load_lds((gvp)(rp + so0), (lvp)lp,         16, 0, 0);
        __builtin_amdgcn_global_load_lds((gvp)(rp + so1), (lvp)(lp + 256), 16, 0, 0);
    };

    // Reader chunk positions (swizzled), fixed across rows: chunks
    // 2l-1 .. 2l+2 = floats 8l-4 .. 8l+11 (clamped + masked at edges).
    const int p0 = swz(max(2 * l - 1, 0));
    const int p1 = swz(2 * l);
    const int p2 = swz(2 * l + 1);
    const int p3 = swz(min(2 * l + 2, 127));
    const float m0 = (l == 0)  ? 0.f : 1.f;   // left-halo zero mask
    const float m3 = (l == 63) ? 0.f : 1.f;   // right-halo zero mask

    const float w0 = 1.f/64.f, w1 = 6.f/64.f, w2 = 15.f/64.f, w3 = 20.f/64.f;

    // ds_read row k from slot sl, horizontal 7-tap blur (stride 2), zero for
    // out-of-image rows (wave-uniform rm).
    auto HROW = [&](int k, int sl) -> float4 {
        const float* rp = rbase + sl * 512;
        const float4 qa = *(const float4*)(rp + 4 * p0);
        const float4 qb = *(const float4*)(rp + 4 * p1);
        const float4 qc = *(const float4*)(rp + 4 * p2);
        const float4 qd = *(const float4*)(rp + 4 * p3);
        const int gy = g0 + k;
        const float rm = ((unsigned)gy < (unsigned)H) ? 1.f : 0.f;
        float r1 = qa.y * m0, r2 = qa.z * m0, r3 = qa.w * m0;
        float r4 = qb.x, r5 = qb.y, r6 = qb.z, r7 = qb.w;
        float r8 = qc.x, r9 = qc.y, r10 = qc.z, r11 = qc.w;
        float r12 = qd.x * m3, r13 = qd.y * m3;
        float4 h;
        h.x = (w0*(r1 + r7)  + w1*(r2 + r6)  + w2*(r3 + r5)  + w3*r4)  * rm;
        h.y = (w0*(r3 + r9)  + w1*(r4 + r8)  + w2*(r5 + r7)  + w3*r6)  * rm;
        h.z = (w0*(r5 + r11) + w1*(r6 + r10) + w2*(r7 + r9)  + w3*r8)  * rm;
        h.w = (w0*(r7 + r13) + w1*(r8 + r12) + w2*(r9 + r11) + w3*r10) * rm;
        return h;
    };

    unsigned int* wh = sh + (tid & (NSH - 1)) * BINS;
    auto binit = [&](float v) {
        int bb = min((int)(v * 25.f), BINS - 1);   // v in [0,1] by construction
        atomicAdd(&wh[bb], 1u);
    };
    auto vout = [&](const float4& h0, const float4& h1, const float4& h2,
                    const float4& h3, const float4& h4, const float4& h5,
                    const float4& h6) {
        binit(w0*(h0.x+h6.x) + w1*(h1.x+h5.x) + w2*(h2.x+h4.x) + w3*h3.x);
        binit(w0*(h0.y+h6.y) + w1*(h1.y+h5.y) + w2*(h2.y+h4.y) + w3*h3.y);
        binit(w0*(h0.z+h6.z) + w1*(h1.z+h5.z) + w2*(h2.z+h4.z) + w3*h3.z);
        binit(w0*(h0.w+h6.w) + w1*(h1.w+h5.w) + w2*(h2.w+h4.w) + w3*h3.w);
    };

    // ---- prologue: fill ring, h-blur rows 0..4 ----
    STAGE(0, 0); STAGE(1, 1); STAGE(2, 2);
    STAGE(3, 3); STAGE(4, 4); STAGE(5, 5);           // 12 DMAs in flight
    asm volatile("s_waitcnt vmcnt(2)" ::: "memory"); // rows 0..4 arrived
    float4 h0 = HROW(0, 0), h1 = HROW(1, 1), h2 = HROW(2, 2),
           h3 = HROW(3, 3), h4 = HROW(4, 4);
    asm volatile("s_waitcnt lgkmcnt(0)" ::: "memory"); // reads retired before overwrite
    STAGE(6, 0); STAGE(7, 1); STAGE(8, 2); STAGE(9, 3);

    // ---- steady state: invariant at iter j: issued <= row 2j+9, read <= 2j+4.
    // vmcnt(6) leaves the newest 3 rows in flight; never drains to 0.
    float4 h5, h6;
    #pragma unroll
    for (int j = 0; j < 16; j++) {
        const int k5 = 2 * j + 5, k6 = 2 * j + 6;
        asm volatile("s_waitcnt vmcnt(6)" ::: "memory");   // rows <= 2j+6 arrived
        h5 = HROW(k5, k5 % RING);
        h6 = HROW(k6, k6 % RING);
        asm volatile("s_waitcnt lgkmcnt(0)" ::: "memory"); // ds_reads done -> slots reusable
        STAGE(2 * j + 10, (2 * j + 10) % RING);
        STAGE(2 * j + 11, (2 * j + 11) % RING);
        vout(h0, h1, h2, h3, h4, h5, h6);
        h0 = h2; h1 = h3; h2 = h4; h3 = h5; h4 = h6;
    }
    asm volatile("s_waitcnt vmcnt(0)" ::: "memory");  // drain tail DMAs pre-exit
    __syncthreads();

    // ---- one histogram writeout per block ----
    if (tid < BINS) {
        unsigned int acc = 0;
        #pragma unroll
        for (int g = 0; g < NSH; g++) acc += sh[g * BINS + tid];
        partial[b * BINS + tid] = acc;
    }
}

// 96 blocks x 64 threads: plane p gathers its 4 block-partials for x and y,
// cosine sim, atomic mean into out[0].
__global__ __launch_bounds__(64) void reduce_cos(
        const unsigned int* __restrict__ partial, float* __restrict__ out) {
    __shared__ float sa[BINS], sb[BINS];
    const int p = blockIdx.x;
    const int t = threadIdx.x;
    if (t < BINS) {
        unsigned int a = 0, bb = 0;
        #pragma unroll
        for (int j = 0; j < BPP; j++) {
            a  += partial[((size_t)p * BPP + j) * BINS + t];
            bb += partial[((size_t)(NPLANES + p) * BPP + j) * BINS + t];
        }
        sa[t] = (float)a;
        sb[t] = (float)bb;
    }
    __syncthreads();
    if (t == 0) {
        const float inv_hw = 1.0f / (float)(H * W);
        float dot = 0.f, nx = 0.f, ny = 0.f;
        for (int k = 0; k < BINS; k++) {
            float a = sa[k] * inv_hw;
            float c = sb[k] * inv_hw;
            dot += a * c;
            nx  += a * a;
            ny  += c * c;
        }
        nx = fmaxf(sqrtf(nx), 1e-6f);
        ny = fmaxf(sqrtf(ny), 1e-6f);
        atomicAdd(out, (dot / (nx * ny)) * (1.0f / (float)NPLANES));
    }
}

extern "C" void kernel_launch(void* const* d_in, const int* in_sizes, int n_in,
                              void* d_out, int out_size, void* d_ws, size_t ws_size,
                              hipStream_t stream) {
    const float* x = (const float*)d_in[0];
    const float* y = (const float*)d_in[1];
    float* out = (float*)d_out;

    unsigned int* partial = (unsigned int*)d_ws;   // [768][25] u32 = 76.8 KB

    hipMemsetAsync(out, 0, sizeof(float), stream);

    blur_hist<<<2 * NPLANES * BPP, 256, 0, stream>>>(x, y, partial);
    reduce_cos<<<NPLANES, 64, 0, stream>>>(partial, out);
}